// Round 1
// baseline (127.909 us; speedup 1.0000x reference)
//
#include <hip/hip_runtime.h>

// SingleRoIExtractor3D fused, two-phase split:
//   K1 mean_kernel: temporal mean feat[N,C,8,16,16] -> featp[N,C,1,16,16]
//      (pure streaming, HBM-bound, 72 MiB traffic)
//   K2 roi_kernel:  block = (roi, 8-channel group) -> perfectly load-balanced
//      aligned RoIAlign from featp (L2/L3-resident), same verified
//      interleaved-LDS 3x3-union separable gather as the previous version.
//
// Rationale: previous single-kernel ran as ONE occupancy round (4096 waves),
// so mean and ROI phases executed in lockstep with no inter-block overlap,
// and blocks of the max-ROI image did ~1.4x the average ROI work. The split
// balances ROI work exactly (1 ROI/block, 8192 blocks) and restores
// pipelining (32 blocks/CU queue depth).

#define NB   4
#define CCH  2048
#define TT   8
#define RR   32
#define PIX  256
#define SCALE (1.0f/16.0f)

// LDS: 4 channels interleaved per pixel (float4); rows padded by one float4.
#define ROWSTRIDE 68              // 16*4 + 4 pad floats
#define GSTRIDE   (16*ROWSTRIDE)  // floats per 4-channel group

__global__ __launch_bounds__(256) void mean_kernel(
    const float* __restrict__ feat, float* __restrict__ featp)
{
    const int tid = threadIdx.x;
    const int n   = blockIdx.x >> 8;          // image
    const int c0  = (blockIdx.x & 255) * 8;   // first of 8 channels
    const int q   = tid & 63;                 // float4 column within frame
    const int w   = tid >> 6;                 // wave id 0..3
#pragma unroll
    for (int cc = 0; cc < 2; ++cc) {
        const int c = w + cc * 4;
        const float4* src = (const float4*)feat +
            (size_t)(n * CCH + c0 + c) * (TT * 64);
        float4 a = src[q];
#pragma unroll
        for (int t = 1; t < TT; ++t) {
            float4 v = src[t * 64 + q];
            a.x += v.x; a.y += v.y; a.z += v.z; a.w += v.w;
        }
        a.x *= 0.125f; a.y *= 0.125f; a.z *= 0.125f; a.w *= 0.125f;
        ((float4*)featp)[(size_t)(n * CCH + c0 + c) * 64 + q] = a;
    }
}

__global__ __launch_bounds__(256) void roi_kernel(
    const float* __restrict__ featp, const float* __restrict__ rois,
    float* __restrict__ out)
{
    __shared__ float sf[2 * GSTRIDE];

    const int tid = threadIdx.x;
    const int r   = blockIdx.x >> 8;          // ROI id
    const int c0  = (blockIdx.x & 255) * 8;   // first of 8 channels

    // ROI params (block-uniform -> scalar loads)
    const int   n    = (int)rois[r * 5 + 0];
    const float bx1  = rois[r * 5 + 1] * SCALE - 0.5f;
    const float by1  = rois[r * 5 + 2] * SCALE - 0.5f;
    const float binw = (rois[r * 5 + 3] * SCALE - 0.5f - bx1) * (1.0f / 16.0f);
    const float binh = (rois[r * 5 + 4] * SCALE - 0.5f - by1) * (1.0f / 16.0f);

    // Issue the staging loads early (featp is L2/L3-resident, just written).
    // 512 float4s per block: thread tid takes #tid (channels 0..3) and
    // #tid+256 (channels 4..7).
    const float4* fp = (const float4*)featp + (size_t)(n * CCH + c0) * 64;
    const float4 v0 = fp[tid];
    const float4 v1 = fp[tid + 256];

    const int oy = tid >> 4, ox = tid & 15;

    // ---- per-pixel separable 3x3 weights (pure VALU, hides under loads) ----
    int Y0, X0;
    float wy0, wy1, wy2, wx0, wx1, wx2;
    {
        float ya = by1 + ((float)(2 * oy) + 0.5f) * 0.5f * binh;
        float yb = ya + 0.5f * binh;
        float m  = (ya >= -1.0f && ya <= 16.0f) ? 1.0f : 0.0f;
        float yc = fminf(fmaxf(ya, 0.0f), 15.0f);
        float yf = floorf(yc);
        Y0 = (int)yf;
        float ly = yc - yf;
        wy0 = (1.0f - ly) * m; wy1 = ly * m; wy2 = 0.0f;
        m  = (yb >= -1.0f && yb <= 16.0f) ? 1.0f : 0.0f;
        yc = fminf(fmaxf(yb, 0.0f), 15.0f);
        yf = floorf(yc);
        ly = yc - yf;
        float hy2 = (1.0f - ly) * m, ly2 = ly * m;
        if ((int)yf > Y0) { wy1 += hy2; wy2 += ly2; }
        else              { wy0 += hy2; wy1 += ly2; }
        wy0 *= 0.25f; wy1 *= 0.25f; wy2 *= 0.25f;  // fold 1/4 sample avg
    }
    {
        float xa = bx1 + ((float)(2 * ox) + 0.5f) * 0.5f * binw;
        float xb = xa + 0.5f * binw;
        float m  = (xa >= -1.0f && xa <= 16.0f) ? 1.0f : 0.0f;
        float xc = fminf(fmaxf(xa, 0.0f), 15.0f);
        float xf = floorf(xc);
        X0 = (int)xf;
        float lx = xc - xf;
        wx0 = (1.0f - lx) * m; wx1 = lx * m; wx2 = 0.0f;
        m  = (xb >= -1.0f && xb <= 16.0f) ? 1.0f : 0.0f;
        xc = fminf(fmaxf(xb, 0.0f), 15.0f);
        xf = floorf(xc);
        lx = xc - xf;
        float hx2 = (1.0f - lx) * m, lx2 = lx * m;
        if ((int)xf > X0) { wx1 += hx2; wx2 += lx2; }
        else              { wx0 += hx2; wx1 += lx2; }
    }

    // ---- stage into interleaved LDS: f[c][y][x] ->
    //      sf[(c>>2)*GSTRIDE + y*ROWSTRIDE + x*4 + (c&3)] ----
    {
        const int c  = tid >> 6;              // 0..3
        const int q  = tid & 63;
        const int y  = q >> 2;
        const int x4 = (q & 3) * 4;
        float* d = sf + y * ROWSTRIDE + x4 * 4 + c;   // group 0 (ch 0..3)
        d[0] = v0.x; d[4] = v0.y; d[8] = v0.z; d[12] = v0.w;
        d += GSTRIDE;                                  // group 1 (ch 4..7)
        d[0] = v1.x; d[4] = v1.y; d[8] = v1.z; d[12] = v1.w;
    }
    __syncthreads();

    const float w00 = wy0 * wx0, w01 = wy0 * wx1, w02 = wy0 * wx2;
    const float w10 = wy1 * wx0, w11 = wy1 * wx1, w12 = wy1 * wx2;
    const float w20 = wy2 * wx0, w21 = wy2 * wx1, w22 = wy2 * wx2;

    const int xi0 = X0, xi1 = min(X0 + 1, 15), xi2 = min(X0 + 2, 15);
    const int yi0 = Y0, yi1 = min(Y0 + 1, 15), yi2 = min(Y0 + 2, 15);

    const bool needx2 = __any(wx2 > 0.0f);   // wave-uniform
    const bool needy2 = __any(wy2 > 0.0f);

#define ACC(W, V) { float4 _t = (V); a.x += (W) * _t.x; a.y += (W) * _t.y; \
                    a.z += (W) * _t.z; a.w += (W) * _t.w; }
    float4 accg[2];
#pragma unroll
    for (int g = 0; g < 2; ++g) {
        const float* base = sf + g * GSTRIDE;
        const float4* r0 = (const float4*)(base + yi0 * ROWSTRIDE);
        const float4* r1 = (const float4*)(base + yi1 * ROWSTRIDE);
        const float4* r2 = (const float4*)(base + yi2 * ROWSTRIDE);
        float4 a = make_float4(0.f, 0.f, 0.f, 0.f);
        ACC(w00, r0[xi0]); ACC(w01, r0[xi1]);
        ACC(w10, r1[xi0]); ACC(w11, r1[xi1]);
        if (needx2) { ACC(w02, r0[xi2]); ACC(w12, r1[xi2]); }
        if (needy2) {
            ACC(w20, r2[xi0]); ACC(w21, r2[xi1]);
            if (needx2) ACC(w22, r2[xi2]);
        }
        accg[g] = a;
    }
#undef ACC

    const size_t ob = ((size_t)r * CCH + c0) * PIX + tid;
    out[ob + 0 * PIX] = accg[0].x;
    out[ob + 1 * PIX] = accg[0].y;
    out[ob + 2 * PIX] = accg[0].z;
    out[ob + 3 * PIX] = accg[0].w;
    out[ob + 4 * PIX] = accg[1].x;
    out[ob + 5 * PIX] = accg[1].y;
    out[ob + 6 * PIX] = accg[1].z;
    out[ob + 7 * PIX] = accg[1].w;
}

extern "C" void kernel_launch(void* const* d_in, const int* in_sizes, int n_in,
                              void* d_out, int out_size, void* d_ws, size_t ws_size,
                              hipStream_t stream)
{
    const float* feat = (const float*)d_in[0];
    const float* rois = (const float*)d_in[1];
    float* out   = (float*)d_out;
    float* featp = out + (size_t)RR * CCH * PIX;   // 2nd tuple output

    // K1: NB * (CCH/8) = 1024 blocks, pure streaming mean
    mean_kernel<<<NB * 256, 256, 0, stream>>>(feat, featp);
    // K2: RR * (CCH/8) = 8192 blocks, one ROI x 8 channels each
    roi_kernel<<<RR * 256, 256, 0, stream>>>(featp, rois, out);
}